// Round 5
// baseline (1362.270 us; speedup 1.0000x reference)
//
#include <hip/hip_runtime.h>
#include <stdint.h>

typedef unsigned short u16;
typedef unsigned int u32;

#define A_TOT 20000
#define L_TOT 80000
#define N_TOT 100000
#define E1 400000
#define E2 800000
#define E_TOT 2000000   // E1 + 2*E2 directed edges (self loops handled separately)

// d_out ELEMENT layout: [0,1.28M) agent_emb | [1.28M,2.56M) xout_A |
// [2.56M,7.68M) lane_emb | [7.68M,12.8M) xout_L   (element = f32 or bf16 per flag)
__device__ __forceinline__ long hoff(int n) {
  return (n < A_TOT) ? 1280000L + (long)n * 64 : 7680000L + (long)(n - A_TOT) * 64;
}

// ---------------- helpers ----------------
__device__ __forceinline__ float bf2f(u16 u) {
  union { u32 i; float f; } v; v.i = ((u32)u) << 16; return v.f;
}
__device__ __forceinline__ u16 f2bf(float f) {
  union { float f; u32 i; } v; v.f = f;
  u32 b = v.i;
  return (u16)((b + 0x7fffu + ((b >> 16) & 1u)) >> 16);
}
// dtype-adaptive scalar load of float input i
__device__ __forceinline__ float loadf(const void* p, long i, bool isf32) {
  return isf32 ? ((const float*)p)[i] : bf2f(((const u16*)p)[i]);
}
typedef __fp16 h16x2 __attribute__((ext_vector_type(2)));
union h2u { h16x2 h; u32 u; };
__device__ __forceinline__ u32 pack2(float lo, float hi) {
  h2u v; v.h = __builtin_amdgcn_cvt_pkrtz(lo, hi); return v.u;
}
__device__ __forceinline__ float fdot2u(u32 a, u32 b, float c) {
  h2u x, y; x.u = a; y.u = b;
#if __has_builtin(__builtin_amdgcn_fdot2)
  return __builtin_amdgcn_fdot2(x.h, y.h, c, false);
#else
  return c + (float)x.h.x * (float)y.h.x + (float)x.h.y * (float)y.h.y;
#endif
}
__device__ __forceinline__ float frcp(float x) {
#if __has_builtin(__builtin_amdgcn_rcpf)
  return __builtin_amdgcn_rcpf(x);
#else
  return 1.f / x;
#endif
}
__device__ __forceinline__ float fsig(float x) { return frcp(1.f + __expf(-x)); }
__device__ __forceinline__ float ftanh(float x) { return 2.f * frcp(1.f + __expf(-2.f * x)) - 1.f; }

// ---------------- dtype probe ----------------
// If agent_hist is f32, the low u16 of each dword is uniform mantissa bits:
// ~47% have bf16-exponent >= 135 (|x|>=2^8). If bf16 pairs of N(0,1): ~0%.
__global__ __launch_bounds__(256) void probe_kernel(const u32* __restrict__ ah, int* __restrict__ flag)
{
  __shared__ int cs[256];
  int bad = 0;
  for (int i = threadIdx.x; i < 1024; i += 256) {
    u32 w = ah[i];
    int e = (w >> 7) & 0xFF;   // exponent of low u16 as bf16
    if (e >= 135) bad++;
  }
  cs[threadIdx.x] = bad;
  __syncthreads();
  for (int o = 128; o > 0; o >>= 1) {
    if (threadIdx.x < o) cs[threadIdx.x] += cs[threadIdx.x + o];
    __syncthreads();
  }
  if (threadIdx.x == 0) *flag = (cs[0] > 100) ? 1 : 0;   // 1 => inputs are f32
}

// ---------------- LSTM ----------------
// One wave = 16 rows; lane = hidden col k; gates i,f,g,o per col. Whh/Wih packed
// fp16-pairs in sW[d2][k*4+g]; h (+x_t) fp16-pairs in sH[d2][row] (stride 68).
// Emits: bf16 internal copy into xh (node-major) AND final output (dtype per flag).
template<int T, int D, bool MEAN>
__device__ void lstm_body(int blk, int nrows, bool isf32,
    const void* __restrict__ xin, const void* __restrict__ Wih,
    const void* __restrict__ Whh, const void* __restrict__ bias,
    u16* __restrict__ xh, void* __restrict__ outv, long obase,
    u32* sW, u32* sH)
{
  constexpr int NP = (D + 1) / 2;   // extra fp16-pairs for x_t
  constexpr int D2 = 32 + NP;       // total pair-iterations
  const int tid = threadIdx.x;

  for (int idx = tid; idx < D2 * 256; idx += 256) {
    int d2 = idx >> 8, jj = idx & 255;
    int k = jj >> 2, g = jj & 3;
    int j = g * 64 + k;
    float lo, hi;
    if (d2 < 32) {
      lo = loadf(Whh, j * 64 + 2 * d2, isf32);
      hi = loadf(Whh, j * 64 + 2 * d2 + 1, isf32);
    } else {
      int p = d2 - 32;
      lo = (2 * p     < D) ? loadf(Wih, j * D + 2 * p, isf32)     : 0.f;
      hi = (2 * p + 1 < D) ? loadf(Wih, j * D + 2 * p + 1, isf32) : 0.f;
    }
    sW[idx] = pack2(lo, hi);
  }
  for (int idx = tid; idx < D2 * 68; idx += 256) sH[idx] = 0;  // h0 = 0
  __syncthreads();

  const int wave = tid >> 6, lane = tid & 63;
  const int r0 = wave * 16;
  const int grow0 = blk * 64 + r0;

  const float bI = loadf(bias, lane, isf32);
  const float bF = loadf(bias, 64 + lane, isf32);
  const float bG = loadf(bias, 128 + lane, isf32);
  const float bO = loadf(bias, 192 + lane, isf32);

  float c[16], ha[16];
#pragma unroll
  for (int i = 0; i < 16; ++i) { c[i] = 0.f; ha[i] = 0.f; }

  const int srr = (NP > 0) ? lane / NP : 0, sp = (NP > 0) ? lane % NP : 0;
  const bool do_stage = (lane < 16 * NP);
  const bool svalid = do_stage && (grow0 + srr < nrows);

  for (int t = 0; t < T; ++t) {
    if (do_stage) {
      float lo = 0.f, hi = 0.f;
      if (svalid) {
        long base = ((long)(grow0 + srr) * T + t) * D + 2 * sp;
        lo = loadf(xin, base, isf32);
        if (2 * sp + 1 < D) hi = loadf(xin, base + 1, isf32);
      }
      sH[(32 + sp) * 68 + r0 + srr] = pack2(lo, hi);
    }
    __syncthreads();

    float aI[16], aF[16], aG[16], aO[16];
#pragma unroll
    for (int i = 0; i < 16; ++i) { aI[i] = bI; aF[i] = bF; aG[i] = bG; aO[i] = bO; }

    for (int d2 = 0; d2 < D2; ++d2) {
      uint4 wv = *(const uint4*)(sW + d2 * 256 + lane * 4);
      uint4 h0 = *(const uint4*)(sH + d2 * 68 + r0);
      uint4 h1 = *(const uint4*)(sH + d2 * 68 + r0 + 4);
      uint4 h2 = *(const uint4*)(sH + d2 * 68 + r0 + 8);
      uint4 h3 = *(const uint4*)(sH + d2 * 68 + r0 + 12);
#define LSTM_ROW(hc, rr) \
      aI[rr] = fdot2u(hc, wv.x, aI[rr]); \
      aF[rr] = fdot2u(hc, wv.y, aF[rr]); \
      aG[rr] = fdot2u(hc, wv.z, aG[rr]); \
      aO[rr] = fdot2u(hc, wv.w, aO[rr]);
      LSTM_ROW(h0.x, 0)  LSTM_ROW(h0.y, 1)  LSTM_ROW(h0.z, 2)  LSTM_ROW(h0.w, 3)
      LSTM_ROW(h1.x, 4)  LSTM_ROW(h1.y, 5)  LSTM_ROW(h1.z, 6)  LSTM_ROW(h1.w, 7)
      LSTM_ROW(h2.x, 8)  LSTM_ROW(h2.y, 9)  LSTM_ROW(h2.z, 10) LSTM_ROW(h2.w, 11)
      LSTM_ROW(h3.x, 12) LSTM_ROW(h3.y, 13) LSTM_ROW(h3.z, 14) LSTM_ROW(h3.w, 15)
#undef LSTM_ROW
    }

#pragma unroll
    for (int rr = 0; rr < 16; ++rr) {
      float si = fsig(aI[rr]);
      float sf = fsig(aF[rr]);
      float tg = ftanh(aG[rr]);
      float so = fsig(aO[rr]);
      float cc = sf * c[rr] + si * tg;
      c[rr] = cc;
      float h = so * ftanh(cc);
      if (MEAN) ha[rr] += h; else ha[rr] = h;
      float hn = __shfl_down(h, 1, 64);
      if ((lane & 1) == 0) {
        sH[(lane >> 1) * 68 + r0 + rr] = pack2(h, hn);
      }
    }
    __syncthreads();
  }

#pragma unroll
  for (int rr = 0; rr < 16; ++rr) {
    int gr = grow0 + rr;
    if (gr < nrows) {
      float v = MEAN ? ha[rr] * (1.f / T) : ha[rr];
      xh[(long)gr * 64 + lane] = f2bf(v);
      long o = obase + (long)gr * 64 + lane;
      if (isf32) ((float*)outv)[o] = v;
      else       ((u16*)outv)[o]   = f2bf(v);
    }
  }
}

#define AGENT_BLOCKS 313   // ceil(20000/64)
#define LANE_BLOCKS 1250   // 80000/64
__global__ __launch_bounds__(256) void lstm_kernel(
    const void* __restrict__ agent_hist, const void* __restrict__ lane_nodes,
    const void* __restrict__ Wih_a, const void* __restrict__ Whh_a, const void* __restrict__ b_a,
    const void* __restrict__ Wih_l, const void* __restrict__ Whh_l, const void* __restrict__ b_l,
    const int* __restrict__ flag, u16* __restrict__ xh, void* __restrict__ outv)
{
  __shared__ u32 sW[35 * 256];
  __shared__ u32 sH[35 * 68];
  const bool isf32 = (*flag != 0);
  if ((int)blockIdx.x < AGENT_BLOCKS) {
    lstm_body<20, 5, false>(blockIdx.x, A_TOT, isf32, agent_hist, Wih_a, Whh_a, b_a,
                            xh, outv, 0L, sW, sH);
  } else {
    lstm_body<10, 2, true>(blockIdx.x - AGENT_BLOCKS, L_TOT, isf32, lane_nodes, Wih_l, Whh_l, b_l,
                           xh + 1280000L, outv, 2560000L, sW, sH);
  }
}

// ---------------- edge / CSR build ----------------
__global__ __launch_bounds__(256) void edge_count_kernel(
    const int* __restrict__ aa, const int* __restrict__ al, int* __restrict__ cnt)
{
  int e = blockIdx.x * 256 + threadIdx.x;
  if (e >= E_TOT) return;
  int d;
  if (e < E1)            d = aa[E1 + e];
  else if (e < E1 + E2)  d = A_TOT + al[E2 + (e - E1)];
  else                   d = al[e - E1 - E2];
  atomicAdd(&cnt[d], 1);
}

__global__ __launch_bounds__(1024) void scan_kernel(const int* __restrict__ cnt, int* __restrict__ rowptr)
{
  __shared__ int lds[1024];
  __shared__ int sbase;
  const int tid = threadIdx.x;
  if (tid == 0) sbase = 0;
  __syncthreads();
  for (int c0 = 0; c0 < N_TOT; c0 += 8192) {
    int base_i = c0 + tid * 8;
    int v[8]; int s = 0;
#pragma unroll
    for (int j = 0; j < 8; ++j) {
      int i = base_i + j;
      v[j] = (i < N_TOT) ? cnt[i] : 0;
      s += v[j];
    }
    lds[tid] = s;
    __syncthreads();
    for (int off = 1; off < 1024; off <<= 1) {
      int t = (tid >= off) ? lds[tid - off] : 0;
      __syncthreads();
      lds[tid] += t;
      __syncthreads();
    }
    int incl = lds[tid];
    int total = lds[1023];
    int run = sbase + incl - s;
#pragma unroll
    for (int j = 0; j < 8; ++j) {
      int i = base_i + j;
      if (i < N_TOT) rowptr[i] = run;
      run += v[j];
    }
    __syncthreads();
    if (tid == 0) sbase += total;
    __syncthreads();
  }
  if (tid == 0) rowptr[N_TOT] = sbase;
}

// packed CSR entry: (src << 14) | qw, qw = round(w * 16383)
__global__ __launch_bounds__(256) void edge_scatter_kernel(
    const int* __restrict__ aa, const int* __restrict__ al,
    const void* __restrict__ laa, const void* __restrict__ lal,
    const void* __restrict__ we, const void* __restrict__ be,
    const int* __restrict__ flag,
    const int* __restrict__ rowptr, int* __restrict__ cur,
    u32* __restrict__ cpk, float* __restrict__ deg)
{
  int e = blockIdx.x * 256 + threadIdx.x;
  if (e >= E_TOT) return;
  const bool f = (*flag != 0);
  int s, d; float len;
  if (e < E1)           { s = aa[e]; d = aa[E1 + e]; len = loadf(laa, e, f); }
  else if (e < E1 + E2) { int i = e - E1; s = al[i]; d = A_TOT + al[E2 + i]; len = loadf(lal, i, f); }
  else                  { int i = e - E1 - E2; s = A_TOT + al[E2 + i]; d = al[i]; len = loadf(lal, i, f); }
  float w = fsig(len * loadf(we, 0, f) + loadf(be, 0, f));
  u32 qw = (u32)(w * 16383.f + 0.5f);
  if (qw > 16383u) qw = 16383u;
  float wq = (float)qw * (1.f / 16383.f);
  int pos = rowptr[d] + atomicAdd(&cur[d], 1);
  cpk[pos] = ((u32)s << 14) | qw;
  atomicAdd(&deg[d], wq);
}

__global__ __launch_bounds__(256) void dinv_kernel(const float* __restrict__ deg, float* __restrict__ dinv)
{
  int n = blockIdx.x * 256 + threadIdx.x;
  if (n < N_TOT) dinv[n] = rsqrtf(deg[n] + 1.0f);  // +1 = self-loop weight
}

// ---------------- GEMM (N x 64) @ (64 x 64) ----------------
// Reads internal bf16 node-major XH; BN=true fuses BN+ReLU on input. Y -> S (bf16).
template<bool BN>
__global__ __launch_bounds__(256) void gemm64_kernel(
    const u16* __restrict__ XH, const void* __restrict__ W, const int* __restrict__ flag,
    u16* __restrict__ Y,
    const float* __restrict__ bnS, const float* __restrict__ bnQ,
    const void* __restrict__ gamma, const void* __restrict__ beta)
{
  __shared__ float Wsh[64 * 64];
  __shared__ float Xsh[64 * 68];
  __shared__ float bA[64], bB[64];
  const int tid = threadIdx.x;
  const bool f = (*flag != 0);
  if (BN && tid < 64) {
    const float invN = 1.f / (float)N_TOT;
    float mu = bnS[tid] * invN;
    float var = bnQ[tid] * invN - mu * mu;
    float iv = rsqrtf(var + 1e-5f);
    float ga = loadf(gamma, tid, f) * iv;
    bA[tid] = ga;
    bB[tid] = loadf(beta, tid, f) - mu * ga;
  }
  for (int i = tid; i < 4096; i += 256) Wsh[i] = loadf(W, i, f);
  __syncthreads();
  const int row0 = blockIdx.x * 64;
  for (int i = tid; i < 512; i += 256) {   // X: 64 rows x 8 col-groups of 8
    int r = i >> 3, cg2 = i & 7;
    int gr = row0 + r;
    float v[8];
    if (gr < N_TOT) {
      uint4 xv = *(const uint4*)(XH + (long)gr * 64 + cg2 * 8);
      v[0] = bf2f((u16)(xv.x & 0xffff)); v[1] = bf2f((u16)(xv.x >> 16));
      v[2] = bf2f((u16)(xv.y & 0xffff)); v[3] = bf2f((u16)(xv.y >> 16));
      v[4] = bf2f((u16)(xv.z & 0xffff)); v[5] = bf2f((u16)(xv.z >> 16));
      v[6] = bf2f((u16)(xv.w & 0xffff)); v[7] = bf2f((u16)(xv.w >> 16));
    } else {
#pragma unroll
      for (int j = 0; j < 8; ++j) v[j] = 0.f;
    }
#pragma unroll
    for (int j = 0; j < 8; ++j) {
      int cc = cg2 * 8 + j;
      float x = v[j];
      if (BN) x = fmaxf(x * bA[cc] + bB[cc], 0.f);
      Xsh[r * 68 + cc] = x;
    }
  }
  __syncthreads();
  const int cg = tid & 15, rg = tid >> 4;
  float acc[4][4];
#pragma unroll
  for (int i = 0; i < 4; ++i)
#pragma unroll
    for (int j = 0; j < 4; ++j) acc[i][j] = 0.f;
  for (int k = 0; k < 64; k += 4) {
    float4 xv0 = *(const float4*)&Xsh[(rg * 4 + 0) * 68 + k];
    float4 xv1 = *(const float4*)&Xsh[(rg * 4 + 1) * 68 + k];
    float4 xv2 = *(const float4*)&Xsh[(rg * 4 + 2) * 68 + k];
    float4 xv3 = *(const float4*)&Xsh[(rg * 4 + 3) * 68 + k];
    float4 w0 = *(const float4*)&Wsh[(k + 0) * 64 + cg * 4];
    float4 w1 = *(const float4*)&Wsh[(k + 1) * 64 + cg * 4];
    float4 w2 = *(const float4*)&Wsh[(k + 2) * 64 + cg * 4];
    float4 w3 = *(const float4*)&Wsh[(k + 3) * 64 + cg * 4];
#define GEMM_ROW(rr, xv) \
    acc[rr][0] += xv.x * w0.x + xv.y * w1.x + xv.z * w2.x + xv.w * w3.x; \
    acc[rr][1] += xv.x * w0.y + xv.y * w1.y + xv.z * w2.y + xv.w * w3.y; \
    acc[rr][2] += xv.x * w0.z + xv.y * w1.z + xv.z * w2.z + xv.w * w3.z; \
    acc[rr][3] += xv.x * w0.w + xv.y * w1.w + xv.z * w2.w + xv.w * w3.w;
    GEMM_ROW(0, xv0) GEMM_ROW(1, xv1) GEMM_ROW(2, xv2) GEMM_ROW(3, xv3)
#undef GEMM_ROW
  }
#pragma unroll
  for (int rr = 0; rr < 4; ++rr) {
    int gr = row0 + rg * 4 + rr;
    if (gr < N_TOT) {
      uint2 pk;
      pk.x = (u32)f2bf(acc[rr][0]) | ((u32)f2bf(acc[rr][1]) << 16);
      pk.y = (u32)f2bf(acc[rr][2]) | ((u32)f2bf(acc[rr][3]) << 16);
      *(uint2*)(Y + (long)gr * 64 + cg * 4) = pk;
    }
  }
}

// ---------------- propagate (gather over packed CSR), one wave per node ----------------
// FINAL=false: write bf16 into XH (node-major). FINAL=true: write d_out (dtype per flag).
template<bool FINAL>
__global__ __launch_bounds__(256) void prop_kernel(
    const u16* __restrict__ S, const int* __restrict__ rowptr,
    const u32* __restrict__ cpk, const float* __restrict__ dinv,
    const void* __restrict__ bias, const int* __restrict__ flag,
    u16* __restrict__ XH, void* __restrict__ outv)
{
  const int lane = threadIdx.x & 63;
  const int n = blockIdx.x * 4 + (threadIdx.x >> 6);  // 25000*4 = N_TOT exact
  const bool f = (*flag != 0);
  const float di = dinv[n];
  const int e0 = rowptr[n], e1 = rowptr[n + 1];
  float acc = bf2f(S[(long)n * 64 + lane]) * di * di;   // self loop, weight 1
  int e = e0;
  for (; e + 4 <= e1; e += 4) {
    u32 p0 = cpk[e], p1 = cpk[e + 1], p2 = cpk[e + 2], p3 = cpk[e + 3];
    int s0 = p0 >> 14, s1 = p1 >> 14, s2 = p2 >> 14, s3 = p3 >> 14;
    float n0 = dinv[s0] * ((float)(p0 & 16383u) * (1.f / 16383.f)) * di;
    float n1 = dinv[s1] * ((float)(p1 & 16383u) * (1.f / 16383.f)) * di;
    float n2 = dinv[s2] * ((float)(p2 & 16383u) * (1.f / 16383.f)) * di;
    float n3 = dinv[s3] * ((float)(p3 & 16383u) * (1.f / 16383.f)) * di;
    acc += bf2f(S[(long)s0 * 64 + lane]) * n0 + bf2f(S[(long)s1 * 64 + lane]) * n1
         + bf2f(S[(long)s2 * 64 + lane]) * n2 + bf2f(S[(long)s3 * 64 + lane]) * n3;
  }
  for (; e < e1; ++e) {
    u32 p = cpk[e];
    int s = p >> 14;
    acc += bf2f(S[(long)s * 64 + lane]) * (dinv[s] * ((float)(p & 16383u) * (1.f / 16383.f)) * di);
  }
  acc += loadf(bias, lane, f);
  if (FINAL) {
    long o = hoff(n) + lane;
    if (f) ((float*)outv)[o] = acc;
    else   ((u16*)outv)[o]   = f2bf(acc);
  } else {
    XH[(long)n * 64 + lane] = f2bf(acc);
  }
}

// ---------------- batchnorm stats (over internal h1 in XH) ----------------
__global__ __launch_bounds__(256) void bnstats_kernel(
    const u16* __restrict__ XH, float* __restrict__ bnS, float* __restrict__ bnQ)
{
  const int c = threadIdx.x & 63, rg = threadIdx.x >> 6;
  float s = 0.f, q = 0.f;
  for (int r = blockIdx.x * 4 + rg; r < N_TOT; r += 256 * 4) {
    float v = bf2f(XH[(long)r * 64 + c]);
    s += v; q += v * v;
  }
  __shared__ float ls[256], lq[256];
  ls[threadIdx.x] = s; lq[threadIdx.x] = q;
  __syncthreads();
  if (threadIdx.x < 64) {
    s = ls[c] + ls[64 + c] + ls[128 + c] + ls[192 + c];
    q = lq[c] + lq[64 + c] + lq[128 + c] + lq[192 + c];
    atomicAdd(&bnS[c], s);
    atomicAdd(&bnQ[c], q);
  }
}

// ---------------- launch ----------------
extern "C" void kernel_launch(void* const* d_in, const int* in_sizes, int n_in,
                              void* d_out, int out_size, void* d_ws, size_t ws_size,
                              hipStream_t stream)
{
  const void* agent_hist = d_in[0];
  const void* lane_nodes = d_in[1];
  const int*  eaa        = (const int*)d_in[2];
  const void* len_aa     = d_in[3];
  const int*  eal        = (const int*)d_in[4];
  const void* len_al     = d_in[5];
  const void* Wih_a = d_in[6];
  const void* Whh_a = d_in[7];
  const void* b_a   = d_in[8];
  const void* Wih_l = d_in[9];
  const void* Whh_l = d_in[10];
  const void* b_l   = d_in[11];
  const void* w_e   = d_in[12];
  const void* b_e   = d_in[13];
  const void* W1    = d_in[14];
  const void* b1    = d_in[15];
  const void* g1    = d_in[16];
  const void* be1   = d_in[17];
  const void* W2    = d_in[18];
  const void* b2    = d_in[19];

  // workspace layout (dword offsets), total ~35.6 MB
  float* ws   = (float*)d_ws;
  u16*   XH   = (u16*)ws;                     // N*64 bf16 (x, then h1)  [0, 3.2M)
  u16*   S    = (u16*)(ws + 3200000);         // N*64 bf16 (GEMM out)    [3.2M, 6.4M)
  u32*   cpk  = (u32*)(ws + 6400000);         // E_TOT packed CSR        [6.4M, 8.4M)
  int*   rowp = (int*)(ws + 8400000);         // N+1
  float* dinv = ws + 8500008;                 // N
  int*   cnt  = (int*)(ws + 8600008);         // N   (zeroed)
  int*   cur  = (int*)(ws + 8700008);         // N   (zeroed)
  float* deg  = ws + 8800008;                 // N   (zeroed)
  float* bnS  = ws + 8900008;                 // 64  (zeroed)
  float* bnQ  = ws + 8900072;                 // 64  (zeroed), end 8,900,136
  int*   flag = (int*)(ws + 8900136);         // dtype flag

  (void)hipMemsetAsync(cnt, 0, (size_t)(8900136 - 8600008) * 4, stream);

  probe_kernel<<<1, 256, 0, stream>>>((const u32*)agent_hist, flag);

  lstm_kernel<<<AGENT_BLOCKS + LANE_BLOCKS, 256, 0, stream>>>(
      agent_hist, lane_nodes, Wih_a, Whh_a, b_a, Wih_l, Whh_l, b_l, flag, XH, d_out);

  int eb = (E_TOT + 255) / 256;
  edge_count_kernel<<<eb, 256, 0, stream>>>(eaa, eal, cnt);
  scan_kernel<<<1, 1024, 0, stream>>>(cnt, rowp);
  edge_scatter_kernel<<<eb, 256, 0, stream>>>(eaa, eal, len_aa, len_al, w_e, b_e,
                                              flag, rowp, cur, cpk, deg);
  dinv_kernel<<<(N_TOT + 255) / 256, 256, 0, stream>>>(deg, dinv);

  int gb = (N_TOT + 63) / 64;
  gemm64_kernel<false><<<gb, 256, 0, stream>>>(XH, W1, flag, S, nullptr, nullptr, nullptr, nullptr);
  prop_kernel<false><<<N_TOT / 4, 256, 0, stream>>>(S, rowp, cpk, dinv, b1, flag, XH, d_out);
  bnstats_kernel<<<256, 256, 0, stream>>>(XH, bnS, bnQ);
  gemm64_kernel<true><<<gb, 256, 0, stream>>>(XH, W2, flag, S, bnS, bnQ, g1, be1);
  prop_kernel<true><<<N_TOT / 4, 256, 0, stream>>>(S, rowp, cpk, dinv, b2, flag, XH, d_out);
}